// Round 5
// baseline (129.145 us; speedup 1.0000x reference)
//
#include <hip/hip_runtime.h>
#include <math.h>

#define IMG   256
#define NFULL 177
#define DETN  362
#define NACQ  45
#define PAD   1024

// ws layout (floats): [0,131072) sino ; [131072,262144) sf
#define SINO_OFF 0
#define SF_OFF   131072

#define TTILE  32
#define HALF_T 180.5f                   // (DETN-1)/2
// Shared tile: 5080 dwords fits 68x74, 72x70, 76x66 (pitch x Hmax).
// 5080*4 + 8 (sRange) + 4 (sSel) + 128 (wparam) = 20460 -> 20480 B LDS block
// -> 8 blocks/CU x 4 waves = 32 waves/CU (LDS and wave limits coincide).
#define TILE_N 5080

__constant__ const int kByOrder[12] = {5, 6, 4, 7, 3, 8, 2, 9, 1, 10, 0, 11};

// ---------------------------------------------------------------------------
// Direct HBM->LDS 16B staging (dest = wave-uniform base + lane*16; our tile
// is linear row-major with pitch == 4*W4, so float4 slot f is lane-contig).
__device__ __forceinline__ void gload16(const float* g, float* l) {
    __builtin_amdgcn_global_load_lds(
        (const __attribute__((address_space(1))) void*)g,
        (__attribute__((address_space(3))) void*)l, 16, 0, 0);
}

// ---------------------------------------------------------------------------
// Radon segment loop, compile-time pitch P and segment length L.
// Per-segment windows (ix0a, iy0, h, interior) are PRECOMPUTED once into LDS
// (threads 0..nseg-1), so the hot loop does one broadcast ds_read_b128
// instead of ~25 redundant VALU per thread per segment.
// Staging is a SINGLE code shape for all segments: pure gload16 stream
// (clamped source coords on boundary segments), followed by a strip-zero
// ds_write pass restoring exact zeros in OOB cells (boundary only). The
// post-staging __syncthreads drains vmcnt(0), so zero-writes cannot race
// the async loads.
template<int P, int L>
__device__ __forceinline__ float radon_core(
    const float* __restrict__ img,
    float* tile, int4* wparam,
    const float c, const float s,
    const float xbase, const float ybase,
    const float xAB_mn, const float yAB_mn, const float yAB_mx,
    const int SloB, const int ShiB, const int tid)
{
    constexpr int W4   = P / 4;
    constexpr int HMAX = TILE_N / P;
    const int ts   = tid & 7;
    const int wid  = tid >> 6;
    const int lane = tid & 63;

    // ---- precompute per-segment windows (nseg <= 8) ----
    const int nseg = (ShiB - SloB + L - 1) / L;
    if (tid < nseg) {
        const int Sseg = SloB + tid * L;
        const float sv0 = (float)Sseg - HALF_T;
        const float sv1 = sv0 + (float)(L - 1);
        const float xmn = xAB_mn - sv1 * s;      // s >= 0 for theta in [0,180)
        const float ya  = sv0 * c, yb = sv1 * c;
        const float ymn = yAB_mn + fminf(ya, yb);
        const float ymx = yAB_mx + fmaxf(ya, yb);
        const int ix0  = (int)floorf(xmn) - 1;
        const int iy0  = (int)floorf(ymn) - 1;
        const int ix0a = ix0 & ~3;
        const int h    = min((int)floorf(ymx) + 3 - iy0, HMAX);
        const int interior = (ix0a >= 0) & (iy0 >= 0) &
                             (ix0a + P <= IMG) & (iy0 + h <= IMG);
        wparam[tid] = make_int4(ix0a, iy0, h, interior);
    }
    __syncthreads();

    float val = 0.0f;
    int seg = 0;
    for (int Sseg = SloB; Sseg < ShiB; Sseg += L, ++seg) {
        const int4 wp = wparam[seg];           // broadcast read
        const int ix0a = wp.x, iy0 = wp.y, h = wp.z, interior = wp.w;
        const int total4 = W4 * h;
        const int nfull  = total4 & ~63;

        if (interior) {
            // clamp-free, predicate-free HBM->LDS stream (common case)
            const float* __restrict__ src = img + iy0 * IMG + ix0a;
            for (int f0 = wid * 64; f0 < nfull; f0 += 256) {
                const int f  = f0 + lane;
                const int r  = f / W4;             // compile-time magic
                const int c4 = f - r * W4;
                gload16(src + r * IMG + (c4 << 2), tile + (f0 << 2));
            }
            const int f = nfull + tid;             // tail (<64), wave 0 only
            if (f < total4) {
                const int r  = f / W4;
                const int c4 = f - r * W4;
                gload16(src + r * IMG + (c4 << 2), tile + (nfull << 2));
            }
        } else {
            // boundary: same stream with clamped coords (garbage lands in
            // OOB cells; fixed by the strip-zero pass below)
            for (int f0 = wid * 64; f0 < nfull; f0 += 256) {
                const int f  = f0 + lane;
                const int r  = f / W4;
                const int c4 = f - r * W4;
                const int py = min(max(iy0 + r, 0), IMG - 1);
                const int px = min(max(ix0a + (c4 << 2), 0), IMG - 4);
                gload16(img + py * IMG + px, tile + (f0 << 2));
            }
            const int f = nfull + tid;
            if (f < total4) {
                const int r  = f / W4;
                const int c4 = f - r * W4;
                const int py = min(max(iy0 + r, 0), IMG - 1);
                const int px = min(max(ix0a + (c4 << 2), 0), IMG - 4);
                gload16(img + py * IMG + px, tile + (nfull << 2));
            }
        }
        __syncthreads();                           // drains vmcnt(0)

        if (!interior) {
            // restore exact zeros in OOB cells (chunk-aligned: ix0a, IMG%4==0)
            const int rlo = min(max(-iy0, 0), h);
            const int rhi = max(min(h, IMG - iy0), rlo);
            const int clo = min(max((-ix0a) >> 2, 0), W4);
            const int chi = max(min((IMG - ix0a) >> 2, W4), clo);
            const float4 z = make_float4(0.f, 0.f, 0.f, 0.f);
            const int nOOB = rlo + (h - rhi);      // fully-OOB rows
            for (int f = tid; f < nOOB * W4; f += 256) {
                const int rr = f / W4;             // compile-time magic
                const int c4 = f - rr * W4;
                const int r  = (rr < rlo) ? rr : rhi + (rr - rlo);
                *(float4*)(tile + r * P + (c4 << 2)) = z;
            }
            const int wside = clo + (W4 - chi);    // OOB cols on valid rows
            if (wside > 0) {
                for (int f = tid; f < ((rhi - rlo) << 5); f += 256) {
                    const int k = f & 31;
                    if (k < wside) {
                        const int r  = rlo + (f >> 5);
                        const int c4 = (k < clo) ? k : chi + (k - clo);
                        *(float4*)(tile + r * P + (c4 << 2)) = z;
                    }
                }
            }
            __syncthreads();
        }

        const float xoff = xbase - (float)ix0a;
        const float yoff = ybase - (float)iy0;
        const int Send = min(Sseg + L, ShiB);

        auto samp = [&](float sval) {
            const float xs  = fmaf(-sval, s, xoff);
            const float ys  = fmaf(sval, c, yoff);
            const float x0f = floorf(xs);
            const float y0f = floorf(ys);
            const float wx  = xs - x0f;
            const float wy  = ys - y0f;
            // base fits exactly in float (< 2^24): saves a cvt+mul
            const int base = (int)fmaf(y0f, (float)P, x0f);
            const float v00 = tile[base];
            const float v01 = tile[base + 1];       // ds_read2 (0,1)
            const float v10 = tile[base + P];
            const float v11 = tile[base + P + 1];   // ds_read2 (P,P+1)
            const float h0 = fmaf(wx, v01 - v00, v00);
            const float h1 = fmaf(wx, v11 - v10, v10);
            val += fmaf(wy, h1 - h0, h0);
        };

        if (Send - Sseg == L) {
            // fast path: compile-time trip count
            const float s0 = (float)(Sseg + ts) - HALF_T;
            #pragma unroll 4
            for (int u = 0; u < L / 8; ++u) samp(s0 + (float)(8 * u));
        } else {
            for (int S = Sseg + ts; S < Send; S += 8) samp((float)S - HALF_T);
        }
        __syncthreads();
    }
    return val;
}

// ---------------------------------------------------------------------------
// Kernel A: radon. Block = (b,angle) x 32-T tile, 256 thr = 32 T x 8 S-phase.
// __launch_bounds__(256,8): cap VGPR<=64 so LDS (20480B -> 8 blocks/CU) binds.
// (P,L) selection inlined on wave 0 (ballot-based bank-multiplicity score).
__global__ __launch_bounds__(256, 8) void radon_kernel(
    const float* __restrict__ x,
    const float* __restrict__ thetas,
    float* __restrict__ sino)
{
    const int blk = blockIdx.x;        // b*NFULL + a
    const int b = blk / NFULL;
    const int a = blk - b * NFULL;
    const int T0 = kByOrder[blockIdx.y] * TTILE;
    const int tid = threadIdx.x;
    const int ts = tid & 7;
    const int tt = tid >> 3;
    const int T = T0 + tt;

    __shared__ __align__(16) float tile[TILE_N];
    __shared__ int4 wparam[8];
    __shared__ int sRange[2];
    __shared__ int sSel;

    const float th = thetas[a] * (float)(M_PI / 180.0);
    const float c = cosf(th);
    const float s = sinf(th);
    const float cx = (IMG - 1) * 0.5f;
    const float cy = (IMG - 1) * 0.5f;
    const float Tc = (float)T - HALF_T;
    const float xbase = Tc * c + cx;   // xs = xbase - sval*s
    const float ybase = Tc * s + cy;   // ys = ybase + sval*c

    // per-thread valid-S clipping -> block union
    float lo = -1e30f, hi = 1e30f;
    bool empty = (T >= DETN);
    {   const float aa = -s;
        if (aa > 1e-5f)       { lo = fmaxf(lo, (-1.0f - xbase) / aa); hi = fminf(hi, (256.0f - xbase) / aa); }
        else if (aa < -1e-5f) { lo = fmaxf(lo, (256.0f - xbase) / aa); hi = fminf(hi, (-1.0f - xbase) / aa); }
        else if (xbase <= -1.0f || xbase >= 256.0f) empty = true;
    }
    {   const float aa = c;
        if (aa > 1e-5f)       { lo = fmaxf(lo, (-1.0f - ybase) / aa); hi = fminf(hi, (256.0f - ybase) / aa); }
        else if (aa < -1e-5f) { lo = fmaxf(lo, (256.0f - ybase) / aa); hi = fminf(hi, (-1.0f - ybase) / aa); }
        else if (ybase <= -1.0f || ybase >= 256.0f) empty = true;
    }
    lo = fmaxf(lo, -200.0f);
    hi = fminf(hi, 200.0f);
    int Slo = max(0, (int)floorf(lo + HALF_T) - 1);
    int Shi = min(DETN, (int)floorf(hi + HALF_T) + 2);
    if (empty || Shi < Slo) { Slo = 0; Shi = 0; }

    if (tid == 0) { sRange[0] = DETN; sRange[1] = 0; }
    __syncthreads();
    if (Shi > Slo) { atomicMin(&sRange[0], Slo); atomicMax(&sRange[1], Shi); }

    // inline (P,L) selection on wave 0 (piggybacks on the sRange barriers).
    // Bank model: lane (ltt,lts) reads at addr ~ ltt*dT + lts*dS, dT=s*P+c,
    // dS=c*P-s; multiplicity via 5-bit ballot match + popcount, wave-max.
    if (tid < 64) {
        const int ltt = tid >> 3, lts = tid & 7;
        const float ac = fabsf(c), as = fabsf(s);
        const float spx = 31.f * ac + 63.f * as;   // spans of 32T x 64S window
        const float spy = 31.f * as + 63.f * ac;
        const int hm[3] = {74, 70, 66};            // TILE_N / P
        int best = 5, bcost = 1 << 30;
        #pragma unroll
        for (int p = 0; p < 3; ++p) {
            const float Pf = 68.f + 4.f * (float)p;
            const float dT = s * Pf + c;
            const float dS = c * Pf - s;
            const int bank = (int)floorf((float)ltt * dT + (float)lts * dS + 0.5f) & 31;
            unsigned long long m = ~0ull;
            #pragma unroll
            for (int bit = 0; bit < 5; ++bit) {
                const unsigned long long bb = __ballot((bank >> bit) & 1);
                m &= ((bank >> bit) & 1) ? bb : ~bb;
            }
            int cnt = __popcll(m);
            #pragma unroll
            for (int d = 1; d < 64; d <<= 1) cnt = max(cnt, __shfl_xor(cnt, d, 64));
            if (spx <= Pf - 8.05f && spy <= (float)hm[p] - 5.05f) {
                if (2 * cnt < bcost) { bcost = 2 * cnt; best = p; }
            }
            // L=48 always fits for P in {68,72,76} (span <= 56.3 <= 59.95)
            if (2 * cnt + 3 < bcost) { bcost = 2 * cnt + 3; best = p + 3; }
        }
        if (tid == 0) sSel = best;
    }
    __syncthreads();
    const int SloB = sRange[0], ShiB = sRange[1];
    const int selv = sSel;

    // hoisted tile-corner terms
    const float TcA = (float)T0 - HALF_T;
    const float TcB = (float)(T0 + TTILE - 1) - HALF_T;
    const float xAB_mn = fminf(TcA * c + cx, TcB * c + cx);
    const float yAB_mn = fminf(TcA * s + cy, TcB * s + cy);
    const float yAB_mx = fmaxf(TcA * s + cy, TcB * s + cy);

    const float* __restrict__ img = x + b * IMG * IMG;

    float val;
    switch (selv) {
    case 0:  val = radon_core<68,64>(img, tile, wparam, c, s, xbase, ybase,
                                     xAB_mn, yAB_mn, yAB_mx, SloB, ShiB, tid); break;
    case 1:  val = radon_core<72,64>(img, tile, wparam, c, s, xbase, ybase,
                                     xAB_mn, yAB_mn, yAB_mx, SloB, ShiB, tid); break;
    case 2:  val = radon_core<76,64>(img, tile, wparam, c, s, xbase, ybase,
                                     xAB_mn, yAB_mn, yAB_mx, SloB, ShiB, tid); break;
    case 3:  val = radon_core<68,48>(img, tile, wparam, c, s, xbase, ybase,
                                     xAB_mn, yAB_mn, yAB_mx, SloB, ShiB, tid); break;
    case 4:  val = radon_core<72,48>(img, tile, wparam, c, s, xbase, ybase,
                                     xAB_mn, yAB_mn, yAB_mx, SloB, ShiB, tid); break;
    default: val = radon_core<76,48>(img, tile, wparam, c, s, xbase, ybase,
                                     xAB_mn, yAB_mn, yAB_mx, SloB, ShiB, tid); break;
    }

    val += __shfl_xor(val, 1, 8);
    val += __shfl_xor(val, 2, 8);
    val += __shfl_xor(val, 4, 8);
    if (ts == 0 && T < DETN) {
        sino[(b * NFULL + a) * DETN + T] = val;
    }
}

// ---------------------------------------------------------------------------
// Kernel B: data-consistency + ramp filter (unchanged).
__global__ __launch_bounds__(192) void dc_filter_kernel(
    const float* __restrict__ sino,
    const float* __restrict__ st,
    const int*   __restrict__ acq,
    float* __restrict__ sf)
{
    const int blk = blockIdx.x;
    const int b = blk / NFULL;
    const int a = blk - b * NFULL;
    const int tid = threadIdx.x;

    __shared__ float col[DETN];
    __shared__ float gf[PAD];

    const float SC = (float)(M_PI / (2.0 * NFULL));
    const float c0 = 0.5f * SC;
    for (int n = tid; n < PAD; n += 192) {
        float v = 0.0f;
        if (n & 1) {
            const int d = (n < PAD - n) ? n : (PAD - n);
            const float pd = (float)M_PI * (float)d;
            v = -2.0f / (pd * pd) * SC;
        }
        gf[n] = v;
    }

    int inv = -1;
    for (int i = 0; i < NACQ; ++i) {
        if (acq[i] == a) inv = i;
    }

    for (int m = tid; m < DETN; m += 192) {
        float val = sino[(b * NFULL + a) * DETN + m];
        if (inv >= 0) {
            val = st[(b * DETN + m) * NACQ + inv] - val;
        }
        col[m] = val;
    }
    __syncthreads();

    const int T = blockIdx.y * 181 + tid;
    if (tid < 181) {
        const int m0 = (T + 1) & 1;
        float acc = c0 * col[T];
        #pragma unroll 4
        for (int k = 0; k < 181; ++k) {
            const int m = m0 + 2 * k;
            acc += col[m] * gf[(T - m) & (PAD - 1)];
        }
        sf[(b * NFULL + a) * DETN + T] = acc;
    }
}

// ---------------------------------------------------------------------------
// Kernel C: backprojection (unchanged).
__global__ __launch_bounds__(256) void backproject_kernel(
    const float* __restrict__ sf,
    const float* __restrict__ thetas,
    float* __restrict__ out)
{
    __shared__ float cb[2 * NFULL];
    __shared__ float red[256];
    const int tid = threadIdx.x;
    const int lane  = tid & 63;
    const int phase = tid >> 6;
    const int pix = blockIdx.x * 64 + lane;
    const int b = pix >> 16;
    const int y = (pix >> 8) & 255;
    const int xq = pix & 255;
    const float gx = (float)xq - (IMG - 1) * 0.5f;
    const float gy = (float)y  - (IMG - 1) * 0.5f;

    for (int a = tid; a < NFULL; a += 256) {
        float th = thetas[a] * (float)(M_PI / 180.0);
        cb[2 * a]     = cosf(th);
        cb[2 * a + 1] = fmaf(sinf(th), gy, HALF_T);
    }
    __syncthreads();

    const float* __restrict__ sfb = sf + b * NFULL * DETN;

    float acc = 0.0f;
    #pragma unroll 4
    for (int a = phase; a < NFULL; a += 4) {
        const float cs = cb[2 * a];
        const float bs = cb[2 * a + 1];
        const float t = fmaf(cs, gx, bs);
        const float t0f = floorf(t);
        const float w = t - t0f;
        const float* row = sfb + a * DETN + (int)t0f;
        const float v0 = row[0];
        const float v1 = row[1];
        acc += v0 + w * (v1 - v0);
    }
    red[tid] = acc;
    __syncthreads();
    if (tid < 64) {
        out[blockIdx.x * 64 + tid] =
            red[tid] + red[tid + 64] + red[tid + 128] + red[tid + 192];
    }
}

extern "C" void kernel_launch(void* const* d_in, const int* in_sizes, int n_in,
                              void* d_out, int out_size, void* d_ws, size_t ws_size,
                              hipStream_t stream) {
    const float* x      = (const float*)d_in[0];
    const float* st     = (const float*)d_in[1];
    const float* thetas = (const float*)d_in[2];
    const int*   acq    = (const int*)d_in[3];
    float* out  = (float*)d_out;
    float* wsf  = (float*)d_ws;
    float* sino = wsf + SINO_OFF;
    float* sf   = wsf + SF_OFF;

    dim3 gA(2 * NFULL, 12);
    radon_kernel<<<gA, 256, 0, stream>>>(x, thetas, sino);
    dim3 gB(2 * NFULL, 2);
    dc_filter_kernel<<<gB, 192, 0, stream>>>(sino, st, acq, sf);
    backproject_kernel<<<(2 * IMG * IMG) / 64, 256, 0, stream>>>(sf, thetas, out);
}

// Round 6
// 126.844 us; speedup vs baseline: 1.0181x; 1.0181x over previous
//
#include <hip/hip_runtime.h>
#include <math.h>

#define IMG   256
#define NFULL 177
#define DETN  362
#define NACQ  45
#define PAD   1024

// ws layout (floats): [0,131072) sino ; [131072,262144) sf
#define SINO_OFF 0
#define SF_OFF   131072

#define TTILE  32
#define HALF_T 180.5f                   // (DETN-1)/2
#define SEGL   32                       // S-samples per segment (double-buffered)
// Per-buffer tile: 2548 dwords fits 44x57, 48x53, 52x49, 56x45, 60x42
// (pitch x Hmax). Worst-case window span (45 deg) = 31*sqrt(2)=43.84:
// P=52 -> 43.95 slack ok, h<=48<=49 ok. Two buffers: 2*2548*4 = 20384 B
// + 12 B (sRange,sSel) = 20396 -> 20480 B LDS block -> 8 blocks/CU,
// 32 waves/CU: double-buffered pipelining WITHOUT losing any occupancy.
#define TILE_SEG 2548

__constant__ const int kByOrder[12] = {5, 6, 4, 7, 3, 8, 2, 9, 1, 10, 0, 11};

// ---------------------------------------------------------------------------
// Direct HBM->LDS 16B staging (dest = wave-uniform base + lane*16; our tile
// is linear row-major with pitch == 4*W4, so float4 slot f is lane-contig).
__device__ __forceinline__ void gload16(const float* g, float* l) {
    __builtin_amdgcn_global_load_lds(
        (const __attribute__((address_space(1))) void*)g,
        (__attribute__((address_space(3))) void*)l, 16, 0, 0);
}

// ---------------------------------------------------------------------------
// Radon segment loop, compile-time pitch P, L=32, double-buffered LDS.
// Pipeline per iteration: issue stage(seg k+1, buf^1) -> sample(seg k, buf)
// -> __syncthreads (drains vmcnt: k+1 loads had the whole sampling phase
// as head start). Single barrier per segment. Buffer swap safety: buf^1 was
// last READ before the previous barrier; all writes (gload16 vmcnt + ds
// lgkm) drain at the barrier before anyone reads the swapped buffer.
template<int P>
__device__ __forceinline__ float radon_core(
    const float* __restrict__ img,
    float* tile,                       // 2*TILE_SEG floats
    const float c, const float s,
    const float xbase, const float ybase,
    const float xAB_mn, const float yAB_mn, const float yAB_mx,
    const int SloB, const int ShiB, const int tid)
{
    constexpr int W4   = P / 4;
    constexpr int HMAX = TILE_SEG / P;
    const int ts   = tid & 7;
    const int wid  = tid >> 6;
    const int lane = tid & 63;

    // per-segment staging window (corner-extreme bounds; covers all 32 T x
    // 32 S taps; fit guaranteed by the sel feasibility check)
    auto window = [&](int Sseg) -> int4 {
        const float sv0 = (float)Sseg - HALF_T;
        const float sv1 = sv0 + (float)(SEGL - 1);
        const float xmn = xAB_mn - sv1 * s;       // s >= 0 for theta in [0,180)
        const float ya  = sv0 * c, yb = sv1 * c;
        const float ymn = yAB_mn + fminf(ya, yb);
        const float ymx = yAB_mx + fmaxf(ya, yb);
        const int ix0  = (int)floorf(xmn) - 1;
        const int iy0  = (int)floorf(ymn) - 1;
        const int ix0a = ix0 & ~3;
        const int h    = min((int)floorf(ymx) + 3 - iy0, HMAX);
        const int inter = (ix0a >= 0) & (iy0 >= 0) &
                          (ix0a + P <= IMG) & (iy0 + h <= IMG);
        return make_int4(ix0a, iy0, h, inter);
    };

    // stage one window into buffer tb. Interior: pure async gload16 stream.
    // Boundary: masked float4 (every cell written; OOB cells exact zeros).
    auto stage = [&](const int4 wp, float* tb) {
        const int total4 = W4 * wp.z;
        const int nfull  = total4 & ~63;
        if (wp.w) {
            const float* __restrict__ src = img + wp.y * IMG + wp.x;
            for (int f0 = wid * 64; f0 < nfull; f0 += 256) {
                const int f  = f0 + lane;
                const int r  = f / W4;             // compile-time magic
                const int c4 = f - r * W4;
                gload16(src + r * IMG + (c4 << 2), tb + (f0 << 2));
            }
            const int f = nfull + tid;             // tail (<64), wave 0 only
            if (f < total4) {
                const int r  = f / W4;
                const int c4 = f - r * W4;
                gload16(src + r * IMG + (c4 << 2), tb + (nfull << 2));
            }
        } else {
            for (int f = tid; f < total4; f += 256) {
                const int r  = f / W4;
                const int c4 = f - r * W4;
                const int gy = wp.y + r;
                const int gx = wp.x + (c4 << 2);   // 4-aligned: all-or-nothing
                const bool ok = ((unsigned)gy < (unsigned)IMG) &
                                ((unsigned)gx <= (unsigned)(IMG - 4));
                float4 v = make_float4(0.f, 0.f, 0.f, 0.f);
                if (ok) v = *(const float4*)(img + gy * IMG + gx);
                *(float4*)(tb + (f << 2)) = v;
            }
        }
    };

    float val = 0.0f;
    if (SloB >= ShiB) return val;

    int4 wp = window(SloB);
    stage(wp, tile);                               // prologue fill buf0
    __syncthreads();

    int cur = 0;
    for (int Sseg = SloB; Sseg < ShiB; Sseg += SEGL) {
        const int Snext = Sseg + SEGL;
        int4 wpn = wp;
        if (Snext < ShiB) {                        // issue next-seg loads FIRST
            wpn = window(Snext);
            stage(wpn, tile + (cur ^ 1) * TILE_SEG);
        }

        const float* __restrict__ tb = tile + cur * TILE_SEG;
        const float xoff = xbase - (float)wp.x;
        const float yoff = ybase - (float)wp.y;
        const int Send = min(Snext, ShiB);

        auto samp = [&](float sval) {
            const float xs  = fmaf(-sval, s, xoff);
            const float ys  = fmaf(sval, c, yoff);
            const float x0f = floorf(xs);
            const float y0f = floorf(ys);
            const float wx  = xs - x0f;
            const float wy  = ys - y0f;
            // base fits exactly in float (< 2^24): saves a cvt+mul
            const int base = (int)fmaf(y0f, (float)P, x0f);
            const float v00 = tb[base];
            const float v01 = tb[base + 1];        // ds_read2 (0,1)
            const float v10 = tb[base + P];
            const float v11 = tb[base + P + 1];    // ds_read2 (P,P+1)
            const float h0 = fmaf(wx, v01 - v00, v00);
            const float h1 = fmaf(wx, v11 - v10, v10);
            val += fmaf(wy, h1 - h0, h0);
        };

        if (Send - Sseg == SEGL) {
            // fast path: compile-time trip count
            const float s0 = (float)(Sseg + ts) - HALF_T;
            #pragma unroll
            for (int u = 0; u < SEGL / 8; ++u) samp(s0 + (float)(8 * u));
        } else {
            for (int S = Sseg + ts; S < Send; S += 8) samp((float)S - HALF_T);
        }
        __syncthreads();                           // drains vmcnt+lgkm, swap safe
        wp = wpn;
        cur ^= 1;
    }
    return val;
}

// ---------------------------------------------------------------------------
// Kernel A: radon. Block = (b,angle) x 32-T tile, 256 thr = 32 T x 8 S-phase.
// __launch_bounds__(256,8): cap VGPR<=64 so LDS (20480B -> 8 blocks/CU) binds.
// Pitch selection inlined on wave 0 (ballot-based bank-multiplicity score
// over P in {44,48,52,56,60}; P=52 always feasible).
__global__ __launch_bounds__(256, 8) void radon_kernel(
    const float* __restrict__ x,
    const float* __restrict__ thetas,
    float* __restrict__ sino)
{
    const int blk = blockIdx.x;        // b*NFULL + a
    const int b = blk / NFULL;
    const int a = blk - b * NFULL;
    const int T0 = kByOrder[blockIdx.y] * TTILE;
    const int tid = threadIdx.x;
    const int ts = tid & 7;
    const int tt = tid >> 3;
    const int T = T0 + tt;

    __shared__ __align__(16) float tile[2 * TILE_SEG];
    __shared__ int sRange[2];
    __shared__ int sSel;

    const float th = thetas[a] * (float)(M_PI / 180.0);
    const float c = cosf(th);
    const float s = sinf(th);
    const float cx = (IMG - 1) * 0.5f;
    const float cy = (IMG - 1) * 0.5f;
    const float Tc = (float)T - HALF_T;
    const float xbase = Tc * c + cx;   // xs = xbase - sval*s
    const float ybase = Tc * s + cy;   // ys = ybase + sval*c

    // per-thread valid-S clipping -> block union
    float lo = -1e30f, hi = 1e30f;
    bool empty = (T >= DETN);
    {   const float aa = -s;
        if (aa > 1e-5f)       { lo = fmaxf(lo, (-1.0f - xbase) / aa); hi = fminf(hi, (256.0f - xbase) / aa); }
        else if (aa < -1e-5f) { lo = fmaxf(lo, (256.0f - xbase) / aa); hi = fminf(hi, (-1.0f - xbase) / aa); }
        else if (xbase <= -1.0f || xbase >= 256.0f) empty = true;
    }
    {   const float aa = c;
        if (aa > 1e-5f)       { lo = fmaxf(lo, (-1.0f - ybase) / aa); hi = fminf(hi, (256.0f - ybase) / aa); }
        else if (aa < -1e-5f) { lo = fmaxf(lo, (256.0f - ybase) / aa); hi = fminf(hi, (-1.0f - ybase) / aa); }
        else if (ybase <= -1.0f || ybase >= 256.0f) empty = true;
    }
    lo = fmaxf(lo, -200.0f);
    hi = fminf(hi, 200.0f);
    int Slo = max(0, (int)floorf(lo + HALF_T) - 1);
    int Shi = min(DETN, (int)floorf(hi + HALF_T) + 2);
    if (empty || Shi < Slo) { Slo = 0; Shi = 0; }

    if (tid == 0) { sRange[0] = DETN; sRange[1] = 0; }
    __syncthreads();
    if (Shi > Slo) { atomicMin(&sRange[0], Slo); atomicMax(&sRange[1], Shi); }

    // inline pitch selection on wave 0 (piggybacks on the sRange barriers).
    // Bank model: lane (ltt,lts) reads at addr ~ ltt*dT + lts*dS, dT=s*P+c,
    // dS=c*P-s; multiplicity via 5-bit ballot match + popcount, wave-max.
    // Feasibility (L=32 windows are x/y-symmetric): span = 31(|c|+|s|)
    // must satisfy span <= P-8.05 and span <= Hmax-5.05. P=52 always fits.
    if (tid < 64) {
        const int ltt = tid >> 3, lts = tid & 7;
        const float ac = fabsf(c), as = fabsf(s);
        const float span = 31.f * (ac + as);       // max 43.84 at 45 deg
        const int hm[5] = {57, 53, 49, 45, 42};    // TILE_SEG / P
        int best = 2, bcost = 1 << 30;             // default P=52
        #pragma unroll
        for (int p = 0; p < 5; ++p) {
            const float Pf = 44.f + 4.f * (float)p;
            const float dT = s * Pf + c;
            const float dS = c * Pf - s;
            const int bank = (int)floorf((float)ltt * dT + (float)lts * dS + 0.5f) & 31;
            unsigned long long m = ~0ull;
            #pragma unroll
            for (int bit = 0; bit < 5; ++bit) {
                const unsigned long long bb = __ballot((bank >> bit) & 1);
                m &= ((bank >> bit) & 1) ? bb : ~bb;
            }
            int cnt = __popcll(m);
            #pragma unroll
            for (int d = 1; d < 64; d <<= 1) cnt = max(cnt, __shfl_xor(cnt, d, 64));
            const bool fit = (span <= Pf - 8.05f) && (span <= (float)hm[p] - 5.05f);
            if (fit && cnt < bcost) { bcost = cnt; best = p; }
        }
        if (tid == 0) sSel = best;
    }
    __syncthreads();
    const int SloB = sRange[0], ShiB = sRange[1];
    const int selv = sSel;

    // hoisted tile-corner terms
    const float TcA = (float)T0 - HALF_T;
    const float TcB = (float)(T0 + TTILE - 1) - HALF_T;
    const float xAB_mn = fminf(TcA * c + cx, TcB * c + cx);
    const float yAB_mn = fminf(TcA * s + cy, TcB * s + cy);
    const float yAB_mx = fmaxf(TcA * s + cy, TcB * s + cy);

    const float* __restrict__ img = x + b * IMG * IMG;

    float val;
    switch (selv) {
    case 0:  val = radon_core<44>(img, tile, c, s, xbase, ybase,
                                  xAB_mn, yAB_mn, yAB_mx, SloB, ShiB, tid); break;
    case 1:  val = radon_core<48>(img, tile, c, s, xbase, ybase,
                                  xAB_mn, yAB_mn, yAB_mx, SloB, ShiB, tid); break;
    case 2:  val = radon_core<52>(img, tile, c, s, xbase, ybase,
                                  xAB_mn, yAB_mn, yAB_mx, SloB, ShiB, tid); break;
    case 3:  val = radon_core<56>(img, tile, c, s, xbase, ybase,
                                  xAB_mn, yAB_mn, yAB_mx, SloB, ShiB, tid); break;
    default: val = radon_core<60>(img, tile, c, s, xbase, ybase,
                                  xAB_mn, yAB_mn, yAB_mx, SloB, ShiB, tid); break;
    }

    val += __shfl_xor(val, 1, 8);
    val += __shfl_xor(val, 2, 8);
    val += __shfl_xor(val, 4, 8);
    if (ts == 0 && T < DETN) {
        sino[(b * NFULL + a) * DETN + T] = val;
    }
}

// ---------------------------------------------------------------------------
// Kernel B: data-consistency + ramp filter (unchanged).
__global__ __launch_bounds__(192) void dc_filter_kernel(
    const float* __restrict__ sino,
    const float* __restrict__ st,
    const int*   __restrict__ acq,
    float* __restrict__ sf)
{
    const int blk = blockIdx.x;
    const int b = blk / NFULL;
    const int a = blk - b * NFULL;
    const int tid = threadIdx.x;

    __shared__ float col[DETN];
    __shared__ float gf[PAD];

    const float SC = (float)(M_PI / (2.0 * NFULL));
    const float c0 = 0.5f * SC;
    for (int n = tid; n < PAD; n += 192) {
        float v = 0.0f;
        if (n & 1) {
            const int d = (n < PAD - n) ? n : (PAD - n);
            const float pd = (float)M_PI * (float)d;
            v = -2.0f / (pd * pd) * SC;
        }
        gf[n] = v;
    }

    int inv = -1;
    for (int i = 0; i < NACQ; ++i) {
        if (acq[i] == a) inv = i;
    }

    for (int m = tid; m < DETN; m += 192) {
        float val = sino[(b * NFULL + a) * DETN + m];
        if (inv >= 0) {
            val = st[(b * DETN + m) * NACQ + inv] - val;
        }
        col[m] = val;
    }
    __syncthreads();

    const int T = blockIdx.y * 181 + tid;
    if (tid < 181) {
        const int m0 = (T + 1) & 1;
        float acc = c0 * col[T];
        #pragma unroll 4
        for (int k = 0; k < 181; ++k) {
            const int m = m0 + 2 * k;
            acc += col[m] * gf[(T - m) & (PAD - 1)];
        }
        sf[(b * NFULL + a) * DETN + T] = acc;
    }
}

// ---------------------------------------------------------------------------
// Kernel C: backprojection (unchanged).
__global__ __launch_bounds__(256) void backproject_kernel(
    const float* __restrict__ sf,
    const float* __restrict__ thetas,
    float* __restrict__ out)
{
    __shared__ float cb[2 * NFULL];
    __shared__ float red[256];
    const int tid = threadIdx.x;
    const int lane  = tid & 63;
    const int phase = tid >> 6;
    const int pix = blockIdx.x * 64 + lane;
    const int b = pix >> 16;
    const int y = (pix >> 8) & 255;
    const int xq = pix & 255;
    const float gx = (float)xq - (IMG - 1) * 0.5f;
    const float gy = (float)y  - (IMG - 1) * 0.5f;

    for (int a = tid; a < NFULL; a += 256) {
        float th = thetas[a] * (float)(M_PI / 180.0);
        cb[2 * a]     = cosf(th);
        cb[2 * a + 1] = fmaf(sinf(th), gy, HALF_T);
    }
    __syncthreads();

    const float* __restrict__ sfb = sf + b * NFULL * DETN;

    float acc = 0.0f;
    #pragma unroll 4
    for (int a = phase; a < NFULL; a += 4) {
        const float cs = cb[2 * a];
        const float bs = cb[2 * a + 1];
        const float t = fmaf(cs, gx, bs);
        const float t0f = floorf(t);
        const float w = t - t0f;
        const float* row = sfb + a * DETN + (int)t0f;
        const float v0 = row[0];
        const float v1 = row[1];
        acc += v0 + w * (v1 - v0);
    }
    red[tid] = acc;
    __syncthreads();
    if (tid < 64) {
        out[blockIdx.x * 64 + tid] =
            red[tid] + red[tid + 64] + red[tid + 128] + red[tid + 192];
    }
}

extern "C" void kernel_launch(void* const* d_in, const int* in_sizes, int n_in,
                              void* d_out, int out_size, void* d_ws, size_t ws_size,
                              hipStream_t stream) {
    const float* x      = (const float*)d_in[0];
    const float* st     = (const float*)d_in[1];
    const float* thetas = (const float*)d_in[2];
    const int*   acq    = (const int*)d_in[3];
    float* out  = (float*)d_out;
    float* wsf  = (float*)d_ws;
    float* sino = wsf + SINO_OFF;
    float* sf   = wsf + SF_OFF;

    dim3 gA(2 * NFULL, 12);
    radon_kernel<<<gA, 256, 0, stream>>>(x, thetas, sino);
    dim3 gB(2 * NFULL, 2);
    dc_filter_kernel<<<gB, 192, 0, stream>>>(sino, st, acq, sf);
    backproject_kernel<<<(2 * IMG * IMG) / 64, 256, 0, stream>>>(sf, thetas, out);
}

// Round 7
// 121.484 us; speedup vs baseline: 1.0631x; 1.0441x over previous
//
#include <hip/hip_runtime.h>
#include <math.h>

#define IMG   256
#define NFULL 177
#define DETN  362
#define NACQ  45
#define PAD   1024

// ws layout (floats): [0,131072) sino ; [131072,262144) sf
#define SINO_OFF 0
#define SF_OFF   131072

#define HALF_T 180.5f                   // (DETN-1)/2
#define SEGL   32                       // S-samples per segment
// Wave-private tile: 1276 dwords. Worst-case 8Tx32S window at 45deg:
// (spanx+12)*(spany+5) <= 1245 < 1276. Two waves/block -> 10208 B LDS
// -> 16 blocks/CU x 2 waves = 32 waves/CU (160 KiB exactly): FULL occupancy
// with ZERO block barriers (all sync is wave-level s_waitcnt).
#define TILE_W 1276

// pair p covers strips {2p, 2p+1} (strip = 8 T's); central pairs first
__constant__ const int kPairOrd[23] =
    {11,10,12,9,13,8,14,7,15,6,16,5,17,4,18,3,19,2,20,1,21,0,22};

// ---------------------------------------------------------------------------
// Direct HBM->LDS 16B staging (dest = wave-uniform base + lane*16).
__device__ __forceinline__ void gload16(const float* g, float* l) {
    __builtin_amdgcn_global_load_lds(
        (const __attribute__((address_space(1))) void*)g,
        (__attribute__((address_space(3))) void*)l, 16, 0, 0);
}

// ---------------------------------------------------------------------------
// One 8-T strip, barrier-free. Per segment: wait prior reads (lgkm), stage
// window into the wave-private buffer (async gload16 interior / masked
// float4 boundary), wave-level drain (vmcnt+lgkm), sample. Window covers
// all 8T x 32S taps (corner-extreme bounds; fit guaranteed by sel check).
template<int P>
__device__ __forceinline__ float radon_strip(
    const float* __restrict__ img,
    float* tb,                          // wave-private TILE_W floats
    const float c, const float s,
    const float xbase, const float ybase,
    const float xAB_mn, const float yAB_mn, const float yAB_mx,
    const int Slo, const int Shi, const int lane)
{
    constexpr int W4   = P / 4;
    constexpr int HMAX = TILE_W / P;
    const int ts = lane & 7;
    float val = 0.0f;

    for (int Sseg = Slo; Sseg < Shi; Sseg += SEGL) {
        // window (s >= 0 for theta in [0,180))
        const float sv0 = (float)Sseg - HALF_T;
        const float sv1 = sv0 + (float)(SEGL - 1);
        const float xmn = xAB_mn - sv1 * s;
        const float ya  = sv0 * c, yb = sv1 * c;
        const float ymn = yAB_mn + fminf(ya, yb);
        const float ymx = yAB_mx + fmaxf(ya, yb);
        const int ix0  = (int)floorf(xmn) - 1;
        const int iy0  = (int)floorf(ymn) - 1;
        const int ix0a = ix0 & ~3;
        const int h    = min((int)floorf(ymx) + 3 - iy0, HMAX);
        const int total4 = W4 * h;
        const int nfull  = total4 & ~63;
        const bool interior = (ix0a >= 0) & (iy0 >= 0) &
                              (ix0a + P <= IMG) & (iy0 + h <= IMG);

        // prior segment's ds_reads must complete before we overwrite tb
        asm volatile("s_waitcnt lgkmcnt(0)" ::: "memory");

        if (interior) {
            // clamp-free, predicate-free async HBM->LDS stream
            const float* __restrict__ src = img + iy0 * IMG + ix0a;
            for (int f0 = 0; f0 < nfull; f0 += 64) {
                const int f  = f0 + lane;
                const int r  = f / W4;             // compile-time magic
                const int c4 = f - r * W4;
                gload16(src + r * IMG + (c4 << 2), tb + (f0 << 2));
            }
            const int f = nfull + lane;            // exec-masked ragged tail
            if (f < total4) {
                const int r  = f / W4;
                const int c4 = f - r * W4;
                gload16(src + r * IMG + (c4 << 2), tb + (nfull << 2));
            }
        } else {
            // boundary: masked float4 (gx 4-aligned, IMG%4==0 -> all-or-nothing)
            for (int f = lane; f < total4; f += 64) {
                const int r  = f / W4;
                const int c4 = f - r * W4;
                const int gy = iy0 + r;
                const int gx = ix0a + (c4 << 2);
                const bool ok = ((unsigned)gy < (unsigned)IMG) &
                                ((unsigned)gx <= (unsigned)(IMG - 4));
                float4 v = make_float4(0.f, 0.f, 0.f, 0.f);
                if (ok) v = *(const float4*)(img + gy * IMG + gx);
                *(float4*)(tb + (f << 2)) = v;
            }
        }
        // wave-level drain: async LDS-writes + ds_writes landed
        asm volatile("s_waitcnt vmcnt(0) lgkmcnt(0)" ::: "memory");
        __builtin_amdgcn_sched_barrier(0);

        const float xoff = xbase - (float)ix0a;
        const float yoff = ybase - (float)iy0;
        const int Send = min(Sseg + SEGL, Shi);

        auto samp = [&](float sval) {
            const float xs  = fmaf(-sval, s, xoff);
            const float ys  = fmaf(sval, c, yoff);
            const float x0f = floorf(xs);
            const float y0f = floorf(ys);
            const float wx  = xs - x0f;
            const float wy  = ys - y0f;
            // base fits exactly in float (< 2^24)
            const int base = (int)fmaf(y0f, (float)P, x0f);
            const float v00 = tb[base];
            const float v01 = tb[base + 1];        // ds_read2 (0,1)
            const float v10 = tb[base + P];
            const float v11 = tb[base + P + 1];    // ds_read2 (P,P+1)
            const float h0 = fmaf(wx, v01 - v00, v00);
            const float h1 = fmaf(wx, v11 - v10, v10);
            val += fmaf(wy, h1 - h0, h0);
        };

        if (Send - Sseg == SEGL) {
            const float s0 = (float)(Sseg + ts) - HALF_T;
            #pragma unroll
            for (int u = 0; u < SEGL / 8; ++u) samp(s0 + (float)(8 * u));
        } else {
            for (int S = Sseg + ts; S < Send; S += 8) samp((float)S - HALF_T);
        }
    }
    return val;
}

// ---------------------------------------------------------------------------
// Kernel A: radon, wave-private. Block = 128 thr = 2 independent waves; each
// wave owns one 8-T strip of one (b,angle). No __syncthreads anywhere.
// Grid: (2*NFULL, 23 strip-pairs), central pairs first. Pitch P selected
// per angle from {16,24,32,36,40,44} by ballot bank-multiplicity score
// among feasible candidates (feasibility margin >= 0.33 over all theta).
__global__ __launch_bounds__(128, 8) void radon_kernel(
    const float* __restrict__ x,
    const float* __restrict__ thetas,
    float* __restrict__ sino)
{
    const int blk = blockIdx.x;        // b*NFULL + a
    const int b = blk / NFULL;
    const int a = blk - b * NFULL;
    const int w    = threadIdx.x >> 6;
    const int lane = threadIdx.x & 63;
    const int sp   = kPairOrd[blockIdx.y] * 2 + w;   // strip 0..45
    const int T0   = sp << 3;
    const int tt   = lane >> 3;
    const int ts   = lane & 7;
    const int T    = T0 + tt;

    __shared__ __align__(16) float tile[2][TILE_W];
    float* tb = tile[w];

    const float th = thetas[a] * (float)(M_PI / 180.0);
    const float c = cosf(th);
    const float s = sinf(th);
    const float cx = (IMG - 1) * 0.5f;
    const float cy = (IMG - 1) * 0.5f;
    const float Tc = (float)T - HALF_T;
    const float xbase = Tc * c + cx;   // xs = xbase - sval*s
    const float ybase = Tc * s + cy;   // ys = ybase + sval*c

    // per-thread valid-S clipping -> wave union (8 T's per wave)
    float lo = -1e30f, hi = 1e30f;
    bool empty = (T >= DETN);
    {   const float aa = -s;
        if (aa > 1e-5f)       { lo = fmaxf(lo, (-1.0f - xbase) / aa); hi = fminf(hi, (256.0f - xbase) / aa); }
        else if (aa < -1e-5f) { lo = fmaxf(lo, (256.0f - xbase) / aa); hi = fminf(hi, (-1.0f - xbase) / aa); }
        else if (xbase <= -1.0f || xbase >= 256.0f) empty = true;
    }
    {   const float aa = c;
        if (aa > 1e-5f)       { lo = fmaxf(lo, (-1.0f - ybase) / aa); hi = fminf(hi, (256.0f - ybase) / aa); }
        else if (aa < -1e-5f) { lo = fmaxf(lo, (256.0f - ybase) / aa); hi = fminf(hi, (-1.0f - ybase) / aa); }
        else if (ybase <= -1.0f || ybase >= 256.0f) empty = true;
    }
    lo = fmaxf(lo, -200.0f);
    hi = fminf(hi, 200.0f);
    int Slo = max(0, (int)floorf(lo + HALF_T) - 1);
    int Shi = min(DETN, (int)floorf(hi + HALF_T) + 2);
    if (empty || Shi < Slo) { Slo = 0; Shi = 0; }

    int wlo = (Shi > Slo) ? Slo : DETN;
    int whi = (Shi > Slo) ? Shi : 0;
    #pragma unroll
    for (int d = 1; d < 64; d <<= 1) {
        wlo = min(wlo, __shfl_xor(wlo, d, 64));
        whi = max(whi, __shfl_xor(whi, d, 64));
    }

    // per-wave pitch selection (registers only; all lanes converge).
    // Bank model: lane (tt,ts) reads at addr ~ tt*dT + ts*dS, dT=s*P+c,
    // dS=c*P-s; multiplicity via 5-bit ballot match + popcount, wave-max.
    // Feasibility: spanx <= P-8.05 and spany <= Hmax-5.05, spans of the
    // 8T x 32S lattice: spanx = 7|c|+31|s|, spany = 7|s|+31|c|.
    int best = 2;                       // P=32 (safety; a feasible cand exists)
    {
        const float ac = fabsf(c), as = fabsf(s);
        const float spanx = 7.f * ac + 31.f * as;
        const float spany = 7.f * as + 31.f * ac;
        const float Pc[6] = {16.f, 24.f, 32.f, 36.f, 40.f, 44.f};
        const int   Hm[6] = {79, 53, 39, 35, 31, 29};   // TILE_W / P
        int bcost = 1 << 30;
        #pragma unroll
        for (int p = 0; p < 6; ++p) {
            const float Pf = Pc[p];
            const float dT = s * Pf + c;
            const float dS = c * Pf - s;
            const int bank = (int)floorf((float)tt * dT + (float)ts * dS + 0.5f) & 31;
            unsigned long long m = ~0ull;
            #pragma unroll
            for (int bit = 0; bit < 5; ++bit) {
                const unsigned long long bb = __ballot((bank >> bit) & 1);
                m &= ((bank >> bit) & 1) ? bb : ~bb;
            }
            int cnt = __popcll(m);
            #pragma unroll
            for (int d = 1; d < 64; d <<= 1) cnt = max(cnt, __shfl_xor(cnt, d, 64));
            const bool fit = (spanx <= Pf - 8.05f) && (spany <= (float)Hm[p] - 5.05f);
            if (fit && cnt < bcost) { bcost = cnt; best = p; }
        }
    }

    // hoisted strip-corner terms (T extremes of this 8-T strip)
    const float TcA = (float)T0 - HALF_T;
    const float TcB = (float)(T0 + 7) - HALF_T;
    const float xAB_mn = fminf(TcA * c + cx, TcB * c + cx);
    const float yAB_mn = fminf(TcA * s + cy, TcB * s + cy);
    const float yAB_mx = fmaxf(TcA * s + cy, TcB * s + cy);

    const float* __restrict__ img = x + b * IMG * IMG;

    float val;
    switch (best) {
    case 0:  val = radon_strip<16>(img, tb, c, s, xbase, ybase,
                                   xAB_mn, yAB_mn, yAB_mx, wlo, whi, lane); break;
    case 1:  val = radon_strip<24>(img, tb, c, s, xbase, ybase,
                                   xAB_mn, yAB_mn, yAB_mx, wlo, whi, lane); break;
    case 2:  val = radon_strip<32>(img, tb, c, s, xbase, ybase,
                                   xAB_mn, yAB_mn, yAB_mx, wlo, whi, lane); break;
    case 3:  val = radon_strip<36>(img, tb, c, s, xbase, ybase,
                                   xAB_mn, yAB_mn, yAB_mx, wlo, whi, lane); break;
    case 4:  val = radon_strip<40>(img, tb, c, s, xbase, ybase,
                                   xAB_mn, yAB_mn, yAB_mx, wlo, whi, lane); break;
    default: val = radon_strip<44>(img, tb, c, s, xbase, ybase,
                                   xAB_mn, yAB_mn, yAB_mx, wlo, whi, lane); break;
    }

    val += __shfl_xor(val, 1, 8);
    val += __shfl_xor(val, 2, 8);
    val += __shfl_xor(val, 4, 8);
    if (ts == 0 && T < DETN) {
        sino[(b * NFULL + a) * DETN + T] = val;
    }
}

// ---------------------------------------------------------------------------
// Kernel B: data-consistency + ramp filter (unchanged).
__global__ __launch_bounds__(192) void dc_filter_kernel(
    const float* __restrict__ sino,
    const float* __restrict__ st,
    const int*   __restrict__ acq,
    float* __restrict__ sf)
{
    const int blk = blockIdx.x;
    const int b = blk / NFULL;
    const int a = blk - b * NFULL;
    const int tid = threadIdx.x;

    __shared__ float col[DETN];
    __shared__ float gf[PAD];

    const float SC = (float)(M_PI / (2.0 * NFULL));
    const float c0 = 0.5f * SC;
    for (int n = tid; n < PAD; n += 192) {
        float v = 0.0f;
        if (n & 1) {
            const int d = (n < PAD - n) ? n : (PAD - n);
            const float pd = (float)M_PI * (float)d;
            v = -2.0f / (pd * pd) * SC;
        }
        gf[n] = v;
    }

    int inv = -1;
    for (int i = 0; i < NACQ; ++i) {
        if (acq[i] == a) inv = i;
    }

    for (int m = tid; m < DETN; m += 192) {
        float val = sino[(b * NFULL + a) * DETN + m];
        if (inv >= 0) {
            val = st[(b * DETN + m) * NACQ + inv] - val;
        }
        col[m] = val;
    }
    __syncthreads();

    const int T = blockIdx.y * 181 + tid;
    if (tid < 181) {
        const int m0 = (T + 1) & 1;
        float acc = c0 * col[T];
        #pragma unroll 4
        for (int k = 0; k < 181; ++k) {
            const int m = m0 + 2 * k;
            acc += col[m] * gf[(T - m) & (PAD - 1)];
        }
        sf[(b * NFULL + a) * DETN + T] = acc;
    }
}

// ---------------------------------------------------------------------------
// Kernel C: backprojection (unchanged).
__global__ __launch_bounds__(256) void backproject_kernel(
    const float* __restrict__ sf,
    const float* __restrict__ thetas,
    float* __restrict__ out)
{
    __shared__ float cb[2 * NFULL];
    __shared__ float red[256];
    const int tid = threadIdx.x;
    const int lane  = tid & 63;
    const int phase = tid >> 6;
    const int pix = blockIdx.x * 64 + lane;
    const int b = pix >> 16;
    const int y = (pix >> 8) & 255;
    const int xq = pix & 255;
    const float gx = (float)xq - (IMG - 1) * 0.5f;
    const float gy = (float)y  - (IMG - 1) * 0.5f;

    for (int a = tid; a < NFULL; a += 256) {
        float th = thetas[a] * (float)(M_PI / 180.0);
        cb[2 * a]     = cosf(th);
        cb[2 * a + 1] = fmaf(sinf(th), gy, HALF_T);
    }
    __syncthreads();

    const float* __restrict__ sfb = sf + b * NFULL * DETN;

    float acc = 0.0f;
    #pragma unroll 4
    for (int a = phase; a < NFULL; a += 4) {
        const float cs = cb[2 * a];
        const float bs = cb[2 * a + 1];
        const float t = fmaf(cs, gx, bs);
        const float t0f = floorf(t);
        const float w = t - t0f;
        const float* row = sfb + a * DETN + (int)t0f;
        const float v0 = row[0];
        const float v1 = row[1];
        acc += v0 + w * (v1 - v0);
    }
    red[tid] = acc;
    __syncthreads();
    if (tid < 64) {
        out[blockIdx.x * 64 + tid] =
            red[tid] + red[tid + 64] + red[tid + 128] + red[tid + 192];
    }
}

extern "C" void kernel_launch(void* const* d_in, const int* in_sizes, int n_in,
                              void* d_out, int out_size, void* d_ws, size_t ws_size,
                              hipStream_t stream) {
    const float* x      = (const float*)d_in[0];
    const float* st     = (const float*)d_in[1];
    const float* thetas = (const float*)d_in[2];
    const int*   acq    = (const int*)d_in[3];
    float* out  = (float*)d_out;
    float* wsf  = (float*)d_ws;
    float* sino = wsf + SINO_OFF;
    float* sf   = wsf + SF_OFF;

    dim3 gA(2 * NFULL, 23);                           // 354 x 23 strip-pairs
    radon_kernel<<<gA, 128, 0, stream>>>(x, thetas, sino);
    dim3 gB(2 * NFULL, 2);
    dc_filter_kernel<<<gB, 192, 0, stream>>>(sino, st, acq, sf);
    backproject_kernel<<<(2 * IMG * IMG) / 64, 256, 0, stream>>>(sf, thetas, out);
}